// Round 1
// baseline (5206.609 us; speedup 1.0000x reference)
//
#include <hip/hip_runtime.h>
#include <math.h>

#define NB 2
#define TSTEPS 288
#define NN 1024
#define DD 64
#define BT (NB*TSTEPS)          // 576
#define ROWS (BT*NN)            // 589824
#define OUT_HALF (ROWS*DD)      // 37748736

// workspace float offsets (total ~4.4 MB)
#define OFF_DIS   0
#define OFF_VA    1024
#define OFF_VB    2048
#define OFF_SCAL  3072
#define OFF_WTH1  3328
#define OFF_BTH1  3520
#define OFF_W02   3584
#define OFF_B02   3776
#define OFF_TEMP  4096
#define OFF_PE    22528
#define OFF_LP    40960

__device__ __forceinline__ unsigned rotl32(unsigned x, int n) {
  return (x << n) | (x >> (32 - n));
}

// JAX threefry bits -> uniform(-1+eps,1) -> sqrt(2)*erfinv (XLA f32 polynomial)
__device__ __forceinline__ float bits_to_normal(unsigned bits) {
  float f = __uint_as_float((bits >> 9) | 0x3f800000u) - 1.0f;  // [0,1)
  const float lo = -0.99999994f;                                 // nextafter(-1,0)
  float u = f * 2.0f + lo;                                       // (hi-lo) rounds to 2.0f
  u = fmaxf(u, lo);
  float w = -log1pf(-u * u);
  float p;
  if (w < 5.0f) {
    w -= 2.5f;
    p = 2.81022636e-08f;
    p = fmaf(p, w, 3.43273939e-07f);
    p = fmaf(p, w, -3.5233877e-06f);
    p = fmaf(p, w, -4.39150654e-06f);
    p = fmaf(p, w, 0.00021858087f);
    p = fmaf(p, w, -0.00125372503f);
    p = fmaf(p, w, -0.00417768164f);
    p = fmaf(p, w, 0.246640727f);
    p = fmaf(p, w, 1.50140941f);
  } else {
    w = sqrtf(w) - 3.0f;
    p = -0.000200214257f;
    p = fmaf(p, w, 0.000100950558f);
    p = fmaf(p, w, 0.00134934322f);
    p = fmaf(p, w, -0.00367342844f);
    p = fmaf(p, w, 0.00573950773f);
    p = fmaf(p, w, -0.0076224613f);
    p = fmaf(p, w, 0.00943887047f);
    p = fmaf(p, w, 1.00167406f);
    p = fmaf(p, w, 2.83297682f);
  }
  return 1.41421356237309515f * (p * u);
}

// v0 = jax.random.normal(key(42), (1024,)) via threefry2x32, key=(0,42), counts=iota
__global__ void k_initv(float* __restrict__ v) {
  int i = threadIdx.x;
  if (i >= 512) return;
  const unsigned k0 = 0u, k1 = 42u;
  const unsigned k2 = 0x1BD11BDAu ^ k0 ^ k1;
  unsigned x0 = (unsigned)i + k0;           // counts[i]
  unsigned x1 = (unsigned)(i + 512) + k1;   // counts[i+512]
#define TF_RND(r) { x0 += x1; x1 = rotl32(x1, r); x1 ^= x0; }
  TF_RND(13) TF_RND(15) TF_RND(26) TF_RND(6)
  x0 += k1; x1 += k2 + 1u;
  TF_RND(17) TF_RND(29) TF_RND(16) TF_RND(24)
  x0 += k2; x1 += k0 + 2u;
  TF_RND(13) TF_RND(15) TF_RND(26) TF_RND(6)
  x0 += k0; x1 += k1 + 3u;
  TF_RND(17) TF_RND(29) TF_RND(16) TF_RND(24)
  x0 += k1; x1 += k2 + 4u;
  TF_RND(13) TF_RND(15) TF_RND(26) TF_RND(6)
  x0 += k2; x1 += k0 + 5u;
#undef TF_RND
  v[i] = bits_to_normal(x0);
  v[i + 512] = bits_to_normal(x1);
}

// dis = (rowsum(A)+1e-12)^-0.5
__global__ void k_rowsum(const float* __restrict__ A, float* __restrict__ dis) {
  __shared__ float red[256];
  int row = blockIdx.x;
  float sm = 0.f;
  for (int j = threadIdx.x; j < NN; j += 256) sm += A[row * NN + j];
  red[threadIdx.x] = sm;
  __syncthreads();
  for (int st = 128; st > 0; st >>= 1) {
    if (threadIdx.x < st) red[threadIdx.x] += red[threadIdx.x + st];
    __syncthreads();
  }
  if (threadIdx.x == 0) dis[row] = 1.0f / sqrtf(red[0] + 1e-12f);
}

// y = L v = v - dis .* (A (dis .* v))
__global__ void k_matvec(const float* __restrict__ A, const float* __restrict__ dis,
                         const float* __restrict__ vin, float* __restrict__ vout) {
  __shared__ float u[NN];
  int t = threadIdx.x;
  for (int j = t; j < NN; j += 256) u[j] = dis[j] * vin[j];
  __syncthreads();
  int lane = t & 63, w = t >> 6;
  for (int r = w; r < 8; r += 4) {
    int row = blockIdx.x * 8 + r;
    const float* Ar = A + row * NN;
    float sm = 0.f;
    for (int j = lane; j < NN; j += 64) sm += Ar[j] * u[j];
    for (int off = 32; off > 0; off >>= 1) sm += __shfl_down(sm, off, 64);
    if (lane == 0) vout[row] = vin[row] - dis[row] * sm;
  }
}

// lam = (v20 . v21) / (v20 . v20), clipped; scal[0] = 2/lam
__global__ void k_lambda(const float* __restrict__ v20, const float* __restrict__ v21,
                         float* __restrict__ scal) {
  __shared__ float r0[256], r1[256];
  int t = threadIdx.x;
  float d0 = 0.f, d1 = 0.f;
  for (int j = t; j < NN; j += 256) { float a = v20[j]; d0 += a * a; d1 += a * v21[j]; }
  r0[t] = d0; r1[t] = d1;
  __syncthreads();
  for (int st = 128; st > 0; st >>= 1) {
    if (t < st) { r0[t] += r0[t + st]; r1[t] += r1[t + st]; }
    __syncthreads();
  }
  if (t == 0) {
    float lam = r1[0] / r0[0];
    lam = fminf(fmaxf(lam, 1e-6f), 2.0f);
    scal[0] = 2.0f / lam;
  }
}

// Lp[i][j] = (s-1)*delta - s*dis_i*dis_j*A_ij   (tildeL)
__global__ void k_build_lp(const float* __restrict__ A, const float* __restrict__ dis,
                           const float* __restrict__ scal, float* __restrict__ Lp) {
  int row = blockIdx.x;
  float s = scal[0];
  float di = dis[row];
  for (int j = threadIdx.x; j < NN; j += 256) {
    float m = (di * A[row * NN + j]) * dis[j];
    float e = (j == row) ? 1.0f : 0.0f;
    Lp[row * NN + j] = s * (e - m) - e;
  }
}

// temp[t][d] = E_d + E_w + E_p ; pe[t][d] = E_p
__global__ void k_temporal(const float* __restrict__ emb_day, const float* __restrict__ emb_week,
                           const int* __restrict__ midx, const int* __restrict__ widx,
                           float* __restrict__ temp, float* __restrict__ pe) {
  int tstep = blockIdx.x, d = threadIdx.x;
  int half = d >> 1;
  float dv = expf((float)(2 * half) * (-0.14391156831212787f));  // -ln(10000)/64
  float ang = (float)tstep * dv;
  float p = (d & 1) ? cosf(ang) : sinf(ang);
  int mi = midx[tstep] % TSTEPS; if (mi < 0) mi += TSTEPS;
  int wi = widx[tstep] % 7;      if (wi < 0) wi += 7;
  float tv = (emb_day[mi * DD + d] + emb_week[wi * DD + d]) + p;
  temp[tstep * DD + d] = tv;
  pe[tstep * DD + d] = p;
}

// Wth1 = W_in @ theta1, bth1 = b_in @ theta1, W02 = W_in @ (theta0-theta2), b02 likewise
__global__ void k_smallmats(const float* __restrict__ W_in, const float* __restrict__ b_in,
                            const float* __restrict__ theta, float* __restrict__ ws) {
  int d = threadIdx.x;  // 0..63
  const float* th0 = theta;
  const float* th1 = theta + DD * DD;
  const float* th2 = theta + 2 * DD * DD;
  for (int c = 0; c < 3; ++c) {
    float s1 = 0.f, s02 = 0.f;
    for (int k = 0; k < DD; ++k) {
      float wv = W_in[c * DD + k];
      s1 = fmaf(wv, th1[k * DD + d], s1);
      s02 = fmaf(wv, th0[k * DD + d] - th2[k * DD + d], s02);
    }
    ws[OFF_WTH1 + c * DD + d] = s1;
    ws[OFF_W02 + c * DD + d] = s02;
  }
  float s1 = 0.f, s02 = 0.f;
  for (int k = 0; k < DD; ++k) {
    float bv = b_in[k];
    s1 = fmaf(bv, th1[k * DD + d], s1);
    s02 = fmaf(bv, th0[k * DD + d] - th2[k * DD + d], s02);
  }
  ws[OFF_BTH1 + d] = s1;
  ws[OFF_B02 + d] = s02;
}

// Xp = X @ W_in + b_in  (materialized into d_out second half)
__global__ void k_xp(const float* __restrict__ X, const float* __restrict__ W_in,
                     const float* __restrict__ b_in, float* __restrict__ Xp) {
  int idx = blockIdx.x * 256 + threadIdx.x;
  int row = idx >> 4, dq = (idx & 15) * 4;
  const float x0 = X[row * 3 + 0], x1 = X[row * 3 + 1], x2 = X[row * 3 + 2];
#pragma unroll
  for (int e = 0; e < 4; ++e) {
    int d = dq + e;
    float sv = x0 * W_in[d];
    sv = fmaf(x1, W_in[DD + d], sv);
    sv = fmaf(x2, W_in[2 * DD + d], sv);
    Xp[(size_t)row * DD + d] = sv + b_in[d];
  }
}

// C[bt] = Lp @ B[bt]; rows-in-lanes, B rows are wave-uniform (scalarizable loads)
__global__ __launch_bounds__(256, 4) void k_gemm(const float* __restrict__ Lp,
                                                 const float* __restrict__ Bm,
                                                 float* __restrict__ Cm) {
  const int row = blockIdx.x * 256 + threadIdx.x;   // 0..1023
  const int bt = blockIdx.y;
  const float* __restrict__ lprow = Lp + row * NN;
  const float* __restrict__ Bbt = Bm + (size_t)bt * (NN * DD);
  float acc[DD];
#pragma unroll
  for (int d = 0; d < DD; ++d) acc[d] = 0.0f;
  for (int j = 0; j < NN; j += 4) {
    float a0 = lprow[j + 0], a1 = lprow[j + 1], a2 = lprow[j + 2], a3 = lprow[j + 3];
    const float* __restrict__ B0 = Bbt + (j + 0) * DD;
    const float* __restrict__ B1 = Bbt + (j + 1) * DD;
    const float* __restrict__ B2 = Bbt + (j + 2) * DD;
    const float* __restrict__ B3 = Bbt + (j + 3) * DD;
#pragma unroll
    for (int d = 0; d < DD; ++d) acc[d] = fmaf(a0, B0[d], acc[d]);
#pragma unroll
    for (int d = 0; d < DD; ++d) acc[d] = fmaf(a1, B1[d], acc[d]);
#pragma unroll
    for (int d = 0; d < DD; ++d) acc[d] = fmaf(a2, B2[d], acc[d]);
#pragma unroll
    for (int d = 0; d < DD; ++d) acc[d] = fmaf(a3, B3[d], acc[d]);
  }
  float* crow = Cm + ((size_t)bt * NN + row) * DD;
#pragma unroll
  for (int d = 0; d < DD; ++d) crow[d] = acc[d];
}

// in-place: U = Xp@theta1 + 2*(T1@theta2)  (Xp@theta1 via X@(W_in theta1))
__global__ __launch_bounds__(256, 3) void k_cheb_u(float* __restrict__ T1U,
    const float* __restrict__ X, const float* __restrict__ th2,
    const float* __restrict__ Wth1, const float* __restrict__ bth1) {
  const int row = blockIdx.x * 256 + threadIdx.x;
  const float x0 = X[row * 3 + 0], x1 = X[row * 3 + 1], x2 = X[row * 3 + 2];
  float* trow = T1U + (size_t)row * DD;
  float t1[DD];
#pragma unroll
  for (int d = 0; d < DD; ++d) t1[d] = trow[d];
  float acc[DD];
#pragma unroll
  for (int d = 0; d < DD; ++d) {
    float s = x0 * Wth1[d];
    s = fmaf(x1, Wth1[DD + d], s);
    s = fmaf(x2, Wth1[2 * DD + d], s);
    acc[d] = s + bth1[d];
  }
  for (int k = 0; k < DD; ++k) {
    const float a = 2.0f * t1[k];
    const float* __restrict__ r = th2 + k * DD;
#pragma unroll
    for (int d = 0; d < DD; ++d) acc[d] = fmaf(a, r[d], acc[d]);
  }
#pragma unroll
  for (int d = 0; d < DD; ++d) trow[d] = acc[d];
}

// X_te = LN(Xp + temp), X_sp = LN(Xp + (X@W02 + b02 + V + cheb_bias) + pe)
__global__ __launch_bounds__(256) void k_final(const float* __restrict__ X,
    const float* __restrict__ W_in, const float* __restrict__ b_in,
    const float* __restrict__ cheb_bias, const float* __restrict__ ln_g,
    const float* __restrict__ ln_b, const float* __restrict__ temp,
    const float* __restrict__ pe, const float* __restrict__ W02,
    const float* __restrict__ b02, float* __restrict__ out_te, float* out_sp) {
  const int t = threadIdx.x;
  const int lane = t & 63;
  const size_t row = (size_t)blockIdx.x * 4 + (t >> 6);
  const int tt = (int)((row >> 10) % TSTEPS);
  const float x0 = X[row * 3 + 0], x1 = X[row * 3 + 1], x2 = X[row * 3 + 2];
  float xp = x0 * W_in[lane];
  xp = fmaf(x1, W_in[DD + lane], xp);
  xp = fmaf(x2, W_in[2 * DD + lane], xp);
  xp += b_in[lane];
  float x02 = x0 * W02[lane];
  x02 = fmaf(x1, W02[DD + lane], x02);
  x02 = fmaf(x2, W02[2 * DD + lane], x02);
  x02 += b02[lane];
  const size_t o = row * DD + lane;
  const float v = out_sp[o];            // V = Lp @ U
  const float es = (x02 + v) + cheb_bias[lane];
  const float g = ln_g[lane], bb = ln_b[lane];
  float a_te = xp + temp[tt * DD + lane];
  float a_sp = (xp + es) + pe[tt * DD + lane];
  // LN(te)
  float s = a_te;
  for (int off = 32; off > 0; off >>= 1) s += __shfl_xor(s, off, 64);
  float m = s * (1.0f / 64.0f);
  float dv = a_te - m;
  float q = dv * dv;
  for (int off = 32; off > 0; off >>= 1) q += __shfl_xor(q, off, 64);
  float var = q * (1.0f / 64.0f);
  out_te[o] = dv * (1.0f / sqrtf(var + 1e-5f)) * g + bb;
  // LN(sp)
  s = a_sp;
  for (int off = 32; off > 0; off >>= 1) s += __shfl_xor(s, off, 64);
  m = s * (1.0f / 64.0f);
  dv = a_sp - m;
  q = dv * dv;
  for (int off = 32; off > 0; off >>= 1) q += __shfl_xor(q, off, 64);
  var = q * (1.0f / 64.0f);
  out_sp[o] = dv * (1.0f / sqrtf(var + 1e-5f)) * g + bb;
}

extern "C" void kernel_launch(void* const* d_in, const int* in_sizes, int n_in,
                              void* d_out, int out_size, void* d_ws, size_t ws_size,
                              hipStream_t stream) {
  (void)in_sizes; (void)n_in; (void)out_size; (void)ws_size;
  const float* X         = (const float*)d_in[0];
  const float* A         = (const float*)d_in[1];
  const float* W_in      = (const float*)d_in[2];
  const float* b_in      = (const float*)d_in[3];
  const float* theta     = (const float*)d_in[4];
  const float* cheb_bias = (const float*)d_in[5];
  const float* emb_day   = (const float*)d_in[6];
  const float* emb_week  = (const float*)d_in[7];
  const float* ln_g      = (const float*)d_in[8];
  const float* ln_b      = (const float*)d_in[9];
  const int*   midx      = (const int*)d_in[10];
  const int*   widx      = (const int*)d_in[11];
  float* out_te = (float*)d_out;
  float* out_sp = (float*)d_out + OUT_HALF;
  float* ws = (float*)d_ws;

  // --- tilde-Laplacian pipeline (small) ---
  k_rowsum<<<NN, 256, 0, stream>>>(A, ws + OFF_DIS);
  k_initv<<<1, 512, 0, stream>>>(ws + OFF_VA);
  for (int it = 0; it < 21; ++it) {   // 20 power steps + 1 extra for lambda
    const float* vin = ws + ((it & 1) ? OFF_VB : OFF_VA);
    float* vout      = ws + ((it & 1) ? OFF_VA : OFF_VB);
    k_matvec<<<128, 256, 0, stream>>>(A, ws + OFF_DIS, vin, vout);
  }
  k_lambda<<<1, 256, 0, stream>>>(ws + OFF_VA, ws + OFF_VB, ws + OFF_SCAL);
  k_build_lp<<<NN, 256, 0, stream>>>(A, ws + OFF_DIS, ws + OFF_SCAL, ws + OFF_LP);
  k_smallmats<<<1, 64, 0, stream>>>(W_in, b_in, theta, ws);
  k_temporal<<<TSTEPS, 64, 0, stream>>>(emb_day, emb_week, midx, widx,
                                        ws + OFF_TEMP, ws + OFF_PE);
  // --- main pipeline ---
  k_xp<<<ROWS / 16, 256, 0, stream>>>(X, W_in, b_in, out_sp);            // Xp -> out_sp
  k_gemm<<<dim3(4, BT), 256, 0, stream>>>(ws + OFF_LP, out_sp, out_te);  // T1 -> out_te
  k_cheb_u<<<ROWS / 256, 256, 0, stream>>>(out_te, X, theta + 2 * DD * DD,
                                           ws + OFF_WTH1, ws + OFF_BTH1); // U in-place
  k_gemm<<<dim3(4, BT), 256, 0, stream>>>(ws + OFF_LP, out_te, out_sp);  // V -> out_sp
  k_final<<<ROWS / 4, 256, 0, stream>>>(X, W_in, b_in, cheb_bias, ln_g, ln_b,
                                        ws + OFF_TEMP, ws + OFF_PE,
                                        ws + OFF_W02, ws + OFF_B02,
                                        out_te, out_sp);
}

// Round 2
// 1311.757 us; speedup vs baseline: 3.9692x; 3.9692x over previous
//
#include <hip/hip_runtime.h>
#include <math.h>

#define NB 2
#define TSTEPS 288
#define NN 1024
#define DD 64
#define BT (NB*TSTEPS)          // 576
#define ROWS (BT*NN)            // 589824
#define OUT_HALF (ROWS*DD)      // 37748736

// workspace float offsets
#define OFF_DIS   0
#define OFF_VA    1024
#define OFF_VB    2048
#define OFF_SCAL  3072
#define OFF_WTH1  3328
#define OFF_BTH1  3520
#define OFF_W02   3584
#define OFF_B02   3776
#define OFF_WTH2  3840
#define OFF_BTH2  4032
#define OFF_TEMP  4096
#define OFF_PE    22528
#define OFF_LP    40960
#define OFF_L2    1089536        // 40960 + 1024*1024
#define OFF_AIMG  2138112        // 1089536 + 1024*1024 ; 8 MB of bf16 tile image follows

typedef short bf16x8 __attribute__((ext_vector_type(8)));
typedef float f32x4  __attribute__((ext_vector_type(4)));

__device__ __forceinline__ unsigned rotl32(unsigned x, int n) {
  return (x << n) | (x >> (32 - n));
}

__device__ __forceinline__ unsigned short f2bf_rne(float v) {
  unsigned u = __float_as_uint(v);
  unsigned r = (u + 0x7FFFu + ((u >> 16) & 1u)) >> 16;
  return (unsigned short)r;
}
__device__ __forceinline__ float bf2f(unsigned short h) {
  return __uint_as_float(((unsigned)h) << 16);
}

__device__ __forceinline__ void glds16(const void* g, void* l) {
  __builtin_amdgcn_global_load_lds(
      (const __attribute__((address_space(1))) unsigned int*)g,
      (__attribute__((address_space(3))) unsigned int*)l, 16, 0, 0);
}

// JAX threefry bits -> uniform(-1+eps,1) -> sqrt(2)*erfinv (XLA f32 polynomial)
__device__ __forceinline__ float bits_to_normal(unsigned bits) {
  float f = __uint_as_float((bits >> 9) | 0x3f800000u) - 1.0f;  // [0,1)
  const float lo = -0.99999994f;                                 // nextafter(-1,0)
  float u = f * 2.0f + lo;
  u = fmaxf(u, lo);
  float w = -log1pf(-u * u);
  float p;
  if (w < 5.0f) {
    w -= 2.5f;
    p = 2.81022636e-08f;
    p = fmaf(p, w, 3.43273939e-07f);
    p = fmaf(p, w, -3.5233877e-06f);
    p = fmaf(p, w, -4.39150654e-06f);
    p = fmaf(p, w, 0.00021858087f);
    p = fmaf(p, w, -0.00125372503f);
    p = fmaf(p, w, -0.00417768164f);
    p = fmaf(p, w, 0.246640727f);
    p = fmaf(p, w, 1.50140941f);
  } else {
    w = sqrtf(w) - 3.0f;
    p = -0.000200214257f;
    p = fmaf(p, w, 0.000100950558f);
    p = fmaf(p, w, 0.00134934322f);
    p = fmaf(p, w, -0.00367342844f);
    p = fmaf(p, w, 0.00573950773f);
    p = fmaf(p, w, -0.0076224613f);
    p = fmaf(p, w, 0.00943887047f);
    p = fmaf(p, w, 1.00167406f);
    p = fmaf(p, w, 2.83297682f);
  }
  return 1.41421356237309515f * (p * u);
}

__global__ void k_initv(float* __restrict__ v) {
  int i = threadIdx.x;
  if (i >= 512) return;
  const unsigned k0 = 0u, k1 = 42u;
  const unsigned k2 = 0x1BD11BDAu ^ k0 ^ k1;
  unsigned x0 = (unsigned)i + k0;
  unsigned x1 = (unsigned)(i + 512) + k1;
#define TF_RND(r) { x0 += x1; x1 = rotl32(x1, r); x1 ^= x0; }
  TF_RND(13) TF_RND(15) TF_RND(26) TF_RND(6)
  x0 += k1; x1 += k2 + 1u;
  TF_RND(17) TF_RND(29) TF_RND(16) TF_RND(24)
  x0 += k2; x1 += k0 + 2u;
  TF_RND(13) TF_RND(15) TF_RND(26) TF_RND(6)
  x0 += k0; x1 += k1 + 3u;
  TF_RND(17) TF_RND(29) TF_RND(16) TF_RND(24)
  x0 += k1; x1 += k2 + 4u;
  TF_RND(13) TF_RND(15) TF_RND(26) TF_RND(6)
  x0 += k2; x1 += k0 + 5u;
#undef TF_RND
  v[i] = bits_to_normal(x0);
  v[i + 512] = bits_to_normal(x1);
}

__global__ void k_rowsum(const float* __restrict__ A, float* __restrict__ dis) {
  __shared__ float red[256];
  int row = blockIdx.x;
  float sm = 0.f;
  for (int j = threadIdx.x; j < NN; j += 256) sm += A[row * NN + j];
  red[threadIdx.x] = sm;
  __syncthreads();
  for (int st = 128; st > 0; st >>= 1) {
    if (threadIdx.x < st) red[threadIdx.x] += red[threadIdx.x + st];
    __syncthreads();
  }
  if (threadIdx.x == 0) dis[row] = 1.0f / sqrtf(red[0] + 1e-12f);
}

__global__ void k_matvec(const float* __restrict__ A, const float* __restrict__ dis,
                         const float* __restrict__ vin, float* __restrict__ vout) {
  __shared__ float u[NN];
  int t = threadIdx.x;
  for (int j = t; j < NN; j += 256) u[j] = dis[j] * vin[j];
  __syncthreads();
  int lane = t & 63, w = t >> 6;
  for (int r = w; r < 8; r += 4) {
    int row = blockIdx.x * 8 + r;
    const float* Ar = A + row * NN;
    float sm = 0.f;
    for (int j = lane; j < NN; j += 64) sm += Ar[j] * u[j];
    for (int off = 32; off > 0; off >>= 1) sm += __shfl_down(sm, off, 64);
    if (lane == 0) vout[row] = vin[row] - dis[row] * sm;
  }
}

__global__ void k_lambda(const float* __restrict__ v20, const float* __restrict__ v21,
                         float* __restrict__ scal) {
  __shared__ float r0[256], r1[256];
  int t = threadIdx.x;
  float d0 = 0.f, d1 = 0.f;
  for (int j = t; j < NN; j += 256) { float a = v20[j]; d0 += a * a; d1 += a * v21[j]; }
  r0[t] = d0; r1[t] = d1;
  __syncthreads();
  for (int st = 128; st > 0; st >>= 1) {
    if (t < st) { r0[t] += r0[t + st]; r1[t] += r1[t + st]; }
    __syncthreads();
  }
  if (t == 0) {
    float lam = r1[0] / r0[0];
    lam = fminf(fmaxf(lam, 1e-6f), 2.0f);
    scal[0] = 2.0f / lam;
  }
}

__global__ void k_build_lp(const float* __restrict__ A, const float* __restrict__ dis,
                           const float* __restrict__ scal, float* __restrict__ Lp) {
  int row = blockIdx.x;
  float s = scal[0];
  float di = dis[row];
  for (int j = threadIdx.x; j < NN; j += 256) {
    float m = (di * A[row * NN + j]) * dis[j];
    float e = (j == row) ? 1.0f : 0.0f;
    Lp[row * NN + j] = s * (e - m) - e;
  }
}

// L2 = Lp @ Lp, fp32 tiled 64x64, thread 4x4
__global__ __launch_bounds__(256) void k_l2(const float* __restrict__ A, float* __restrict__ C) {
  __shared__ float sa[64][34];
  __shared__ float sb[32][64];
  int t = threadIdx.x;
  int bx = blockIdx.x & 15, by = blockIdx.x >> 4;
  int r0 = by * 64, c0 = bx * 64;
  int tx = t & 15, ty = t >> 4;
  float acc[4][4] = {};
  for (int k0 = 0; k0 < 1024; k0 += 32) {
    {
      int row = t >> 2, kc = (t & 3) * 8;
      const float* g = A + (size_t)(r0 + row) * 1024 + k0 + kc;
      float4 va = *(const float4*)g;
      float4 vb = *(const float4*)(g + 4);
      sa[row][kc + 0] = va.x; sa[row][kc + 1] = va.y; sa[row][kc + 2] = va.z; sa[row][kc + 3] = va.w;
      sa[row][kc + 4] = vb.x; sa[row][kc + 5] = vb.y; sa[row][kc + 6] = vb.z; sa[row][kc + 7] = vb.w;
      int kr = t >> 3, cc = (t & 7) * 8;
      const float* gb = A + (size_t)(k0 + kr) * 1024 + c0 + cc;
      *(float4*)&sb[kr][cc] = *(const float4*)gb;
      *(float4*)&sb[kr][cc + 4] = *(const float4*)(gb + 4);
    }
    __syncthreads();
#pragma unroll 8
    for (int kk = 0; kk < 32; ++kk) {
      float4 bv = *(const float4*)&sb[kk][tx * 4];
#pragma unroll
      for (int i = 0; i < 4; ++i) {
        float a = sa[ty * 4 + i][kk];
        acc[i][0] = fmaf(a, bv.x, acc[i][0]);
        acc[i][1] = fmaf(a, bv.y, acc[i][1]);
        acc[i][2] = fmaf(a, bv.z, acc[i][2]);
        acc[i][3] = fmaf(a, bv.w, acc[i][3]);
      }
    }
    __syncthreads();
  }
#pragma unroll
  for (int i = 0; i < 4; ++i) {
    float4 o; o.x = acc[i][0]; o.y = acc[i][1]; o.z = acc[i][2]; o.w = acc[i][3];
    *(float4*)&C[(size_t)(r0 + ty * 4 + i) * 1024 + c0 + tx * 4] = o;
  }
}

// Build swizzled bf16 hi/lo tile image of A_wide = [Lp | L2].
// Image layout: [rb 0..3][ks 0..63][256 rows x 128B], row = 64B hi + 64B lo,
// 16B chunks XOR-swizzled by ((row&7)<<4).
__global__ void k_split(const float* __restrict__ Lp, const float* __restrict__ L2,
                        unsigned char* __restrict__ Aimg) {
  int g = blockIdx.x * 256 + threadIdx.x;   // 0..262143
  int row = g >> 8;
  int oct = g & 255;
  int k0 = oct * 8;
  const float* src = (k0 < 1024) ? (Lp + (size_t)row * 1024 + k0)
                                 : (L2 + (size_t)row * 1024 + (k0 - 1024));
  bf16x8 hv, lv;
#pragma unroll
  for (int i = 0; i < 8; ++i) {
    float v = src[i];
    unsigned short h = f2bf_rne(v);
    hv[i] = (short)h;
    lv[i] = (short)f2bf_rne(v - bf2f(h));
  }
  int rb = row >> 8, r = row & 255;
  int ks = k0 >> 5, chunk = (k0 >> 3) & 3;
  int swz = (r & 7) << 4;
  size_t tile = ((size_t)(rb * 64 + ks)) * 32768;
  *(bf16x8*)(Aimg + tile + r * 128 + ((chunk * 16) ^ swz)) = hv;
  *(bf16x8*)(Aimg + tile + r * 128 + ((64 + chunk * 16) ^ swz)) = lv;
}

__global__ void k_temporal(const float* __restrict__ emb_day, const float* __restrict__ emb_week,
                           const int* __restrict__ midx, const int* __restrict__ widx,
                           float* __restrict__ temp, float* __restrict__ pe) {
  int tstep = blockIdx.x, d = threadIdx.x;
  int half = d >> 1;
  float dv = expf((float)(2 * half) * (-0.14391156831212787f));
  float ang = (float)tstep * dv;
  float p = (d & 1) ? cosf(ang) : sinf(ang);
  int mi = midx[tstep] % TSTEPS; if (mi < 0) mi += TSTEPS;
  int wi = widx[tstep] % 7;      if (wi < 0) wi += 7;
  float tv = (emb_day[mi * DD + d] + emb_week[wi * DD + d]) + p;
  temp[tstep * DD + d] = tv;
  pe[tstep * DD + d] = p;
}

// WB1 = W_in@th1, bB1 = b_in@th1, W02 = W_in@(th0-th2), b02 likewise,
// WB2 = 2*W_in@th2, bB2 = 2*b_in@th2
__global__ void k_smallmats(const float* __restrict__ W_in, const float* __restrict__ b_in,
                            const float* __restrict__ theta, float* __restrict__ ws) {
  int d = threadIdx.x;  // 0..63
  const float* th0 = theta;
  const float* th1 = theta + DD * DD;
  const float* th2 = theta + 2 * DD * DD;
  for (int c = 0; c < 3; ++c) {
    float s1 = 0.f, s02 = 0.f, s2 = 0.f;
    for (int k = 0; k < DD; ++k) {
      float wv = W_in[c * DD + k];
      s1 = fmaf(wv, th1[k * DD + d], s1);
      s02 = fmaf(wv, th0[k * DD + d] - th2[k * DD + d], s02);
      s2 = fmaf(2.0f * wv, th2[k * DD + d], s2);
    }
    ws[OFF_WTH1 + c * DD + d] = s1;
    ws[OFF_W02 + c * DD + d] = s02;
    ws[OFF_WTH2 + c * DD + d] = s2;
  }
  float s1 = 0.f, s02 = 0.f, s2 = 0.f;
  for (int k = 0; k < DD; ++k) {
    float bv = b_in[k];
    s1 = fmaf(bv, th1[k * DD + d], s1);
    s02 = fmaf(bv, th0[k * DD + d] - th2[k * DD + d], s02);
    s2 = fmaf(2.0f * bv, th2[k * DD + d], s2);
  }
  ws[OFF_BTH1 + d] = s1;
  ws[OFF_B02 + d] = s02;
  ws[OFF_BTH2 + d] = s2;
}

// V_direct[bt] = [Lp | L2] @ [Xp@th1 ; 2*Xp@th2]  via bf16 hi/lo x3 MFMA.
// Block: 256 rows x (2 bt x 64 cols); KT=32; A from pre-swizzled global image via
// global_load_lds; B produced on the fly from X with 3-FMA per value.
__global__ __launch_bounds__(256, 2) void k_gemm_mfma(
    const float* __restrict__ X, const unsigned char* __restrict__ Aimg,
    const float* __restrict__ ws, float* __restrict__ out_sp) {
  __shared__ __align__(16) unsigned char sA[32768];  // 256 rows x 128B
  __shared__ __align__(16) unsigned char sB[16384];  // 128 cols x 128B
  int b = blockIdx.x;                 // 0..1151
  int x = b & 7, jj = b >> 3;
  int rb = x >> 1;                    // XCD-pinned A row-block (2MB slice, L2-resident)
  int btq = (x & 1) * 144 + jj;       // 0..287
  int bt0 = btq * 2;
  int t = threadIdx.x;
  int lane = t & 63;
  int w = t >> 6;                     // wave id = k-octet for producer
  // hoisted producer weights (column = lane)
  float w1_0 = ws[OFF_WTH1 + lane], w1_1 = ws[OFF_WTH1 + 64 + lane], w1_2 = ws[OFF_WTH1 + 128 + lane];
  float bb1  = ws[OFF_BTH1 + lane];
  float w2_0 = ws[OFF_WTH2 + lane], w2_1 = ws[OFF_WTH2 + 64 + lane], w2_2 = ws[OFF_WTH2 + 128 + lane];
  float bb2  = ws[OFF_BTH2 + lane];

  f32x4 acc[4][8];
#pragma unroll
  for (int mf = 0; mf < 4; ++mf)
#pragma unroll
    for (int nf = 0; nf < 8; ++nf) { acc[mf][nf][0] = 0.f; acc[mf][nf][1] = 0.f; acc[mf][nf][2] = 0.f; acc[mf][nf][3] = 0.f; }

  const int off_hl = ((lane >> 4) * 16) ^ ((lane & 7) << 4);
  const int m0 = w * 64;              // wave's row base in block tile
  const unsigned char* tile0 = Aimg + (size_t)rb * 64 * 32768 + t * 16;

  for (int ks = 0; ks < 64; ++ks) {
    // ---- stage A (glds, linear dest; source image is pre-swizzled) ----
    const unsigned char* gsrc = tile0 + (size_t)ks * 32768;
#pragma unroll
    for (int i = 0; i < 8; ++i)
      glds16(gsrc + i * 4096, sA + i * 4096 + t * 16);
    // ---- produce B (hi/lo, swizzled) ----
    {
      int h1 = (ks < 32);
      int jrow = (ks & 31) * 32 + (w << 3);
#pragma unroll
      for (int btl = 0; btl < 2; ++btl) {
        const float* xr = X + (((size_t)(bt0 + btl) << 10) + jrow) * 3;
        bf16x8 hv, lv;
#pragma unroll
        for (int i = 0; i < 8; ++i) {
          float x0 = xr[i * 3], x1 = xr[i * 3 + 1], x2 = xr[i * 3 + 2];
          float v = h1 ? fmaf(x2, w1_2, fmaf(x1, w1_1, fmaf(x0, w1_0, bb1)))
                       : fmaf(x2, w2_2, fmaf(x1, w2_1, fmaf(x0, w2_0, bb2)));
          unsigned short h = f2bf_rne(v);
          hv[i] = (short)h;
          lv[i] = (short)f2bf_rne(v - bf2f(h));
        }
        int ccol = btl * 64 + lane;
        int base = ccol * 128;
        int swz = (ccol & 7) << 4;
        *(bf16x8*)(sB + base + ((w * 16) ^ swz)) = hv;
        *(bf16x8*)(sB + base + ((64 + w * 16) ^ swz)) = lv;
      }
    }
    __syncthreads();
    // ---- consume: frags + 96 MFMA ----
    bf16x8 Ah[4], Al[4];
#pragma unroll
    for (int mf = 0; mf < 4; ++mf) {
      const unsigned char* ab = sA + (m0 + mf * 16 + (lane & 15)) * 128;
      Ah[mf] = *(const bf16x8*)(ab + off_hl);
      Al[mf] = *(const bf16x8*)(ab + (off_hl ^ 64));
    }
#pragma unroll
    for (int nf = 0; nf < 8; ++nf) {
      const unsigned char* bb = sB + (nf * 16 + (lane & 15)) * 128;
      bf16x8 Bh = *(const bf16x8*)(bb + off_hl);
      bf16x8 Bl = *(const bf16x8*)(bb + (off_hl ^ 64));
#pragma unroll
      for (int mf = 0; mf < 4; ++mf) {
        acc[mf][nf] = __builtin_amdgcn_mfma_f32_16x16x32_bf16(Ah[mf], Bh, acc[mf][nf], 0, 0, 0);
        acc[mf][nf] = __builtin_amdgcn_mfma_f32_16x16x32_bf16(Ah[mf], Bl, acc[mf][nf], 0, 0, 0);
        acc[mf][nf] = __builtin_amdgcn_mfma_f32_16x16x32_bf16(Al[mf], Bh, acc[mf][nf], 0, 0, 0);
      }
    }
    __syncthreads();
  }
  // ---- store V_direct to out_sp ----
#pragma unroll
  for (int nf = 0; nf < 8; ++nf) {
    int btl = nf >> 2;
    int col = (nf & 3) * 16 + (lane & 15);
    size_t base = (((size_t)(bt0 + btl) << 10) + rb * 256 + m0) * 64 + col;
#pragma unroll
    for (int mf = 0; mf < 4; ++mf) {
      int rp = mf * 16 + (lane >> 4) * 4;
#pragma unroll
      for (int i = 0; i < 4; ++i)
        out_sp[base + (size_t)(rp + i) * 64] = acc[mf][nf][i];
    }
  }
}

// X_te = LN(Xp + temp), X_sp = LN(Xp + (X@W02 + b02 + V + cheb_bias) + pe)
__global__ __launch_bounds__(256) void k_final(const float* __restrict__ X,
    const float* __restrict__ W_in, const float* __restrict__ b_in,
    const float* __restrict__ cheb_bias, const float* __restrict__ ln_g,
    const float* __restrict__ ln_b, const float* __restrict__ temp,
    const float* __restrict__ pe, const float* __restrict__ W02,
    const float* __restrict__ b02, float* __restrict__ out_te, float* out_sp) {
  const int t = threadIdx.x;
  const int lane = t & 63;
  const size_t row = (size_t)blockIdx.x * 4 + (t >> 6);
  const int tt = (int)((row >> 10) % TSTEPS);
  const float x0 = X[row * 3 + 0], x1 = X[row * 3 + 1], x2 = X[row * 3 + 2];
  float xp = x0 * W_in[lane];
  xp = fmaf(x1, W_in[DD + lane], xp);
  xp = fmaf(x2, W_in[2 * DD + lane], xp);
  xp += b_in[lane];
  float x02 = x0 * W02[lane];
  x02 = fmaf(x1, W02[DD + lane], x02);
  x02 = fmaf(x2, W02[2 * DD + lane], x02);
  x02 += b02[lane];
  const size_t o = row * DD + lane;
  const float v = out_sp[o];            // V_direct
  const float es = (x02 + v) + cheb_bias[lane];
  const float g = ln_g[lane], bb = ln_b[lane];
  float a_te = xp + temp[tt * DD + lane];
  float a_sp = (xp + es) + pe[tt * DD + lane];
  float s = a_te;
  for (int off = 32; off > 0; off >>= 1) s += __shfl_xor(s, off, 64);
  float m = s * (1.0f / 64.0f);
  float dv = a_te - m;
  float q = dv * dv;
  for (int off = 32; off > 0; off >>= 1) q += __shfl_xor(q, off, 64);
  float var = q * (1.0f / 64.0f);
  out_te[o] = dv * (1.0f / sqrtf(var + 1e-5f)) * g + bb;
  s = a_sp;
  for (int off = 32; off > 0; off >>= 1) s += __shfl_xor(s, off, 64);
  m = s * (1.0f / 64.0f);
  dv = a_sp - m;
  q = dv * dv;
  for (int off = 32; off > 0; off >>= 1) q += __shfl_xor(q, off, 64);
  var = q * (1.0f / 64.0f);
  out_sp[o] = dv * (1.0f / sqrtf(var + 1e-5f)) * g + bb;
}

extern "C" void kernel_launch(void* const* d_in, const int* in_sizes, int n_in,
                              void* d_out, int out_size, void* d_ws, size_t ws_size,
                              hipStream_t stream) {
  (void)in_sizes; (void)n_in; (void)out_size; (void)ws_size;
  const float* X         = (const float*)d_in[0];
  const float* A         = (const float*)d_in[1];
  const float* W_in      = (const float*)d_in[2];
  const float* b_in      = (const float*)d_in[3];
  const float* theta     = (const float*)d_in[4];
  const float* cheb_bias = (const float*)d_in[5];
  const float* emb_day   = (const float*)d_in[6];
  const float* emb_week  = (const float*)d_in[7];
  const float* ln_g      = (const float*)d_in[8];
  const float* ln_b      = (const float*)d_in[9];
  const int*   midx      = (const int*)d_in[10];
  const int*   widx      = (const int*)d_in[11];
  float* out_te = (float*)d_out;
  float* out_sp = (float*)d_out + OUT_HALF;
  float* ws = (float*)d_ws;
  unsigned char* Aimg = (unsigned char*)(ws + OFF_AIMG);

  // --- tilde-Laplacian pipeline (small) ---
  k_rowsum<<<NN, 256, 0, stream>>>(A, ws + OFF_DIS);
  k_initv<<<1, 512, 0, stream>>>(ws + OFF_VA);
  for (int it = 0; it < 21; ++it) {
    const float* vin = ws + ((it & 1) ? OFF_VB : OFF_VA);
    float* vout      = ws + ((it & 1) ? OFF_VA : OFF_VB);
    k_matvec<<<128, 256, 0, stream>>>(A, ws + OFF_DIS, vin, vout);
  }
  k_lambda<<<1, 256, 0, stream>>>(ws + OFF_VA, ws + OFF_VB, ws + OFF_SCAL);
  k_build_lp<<<NN, 256, 0, stream>>>(A, ws + OFF_DIS, ws + OFF_SCAL, ws + OFF_LP);
  k_l2<<<256, 256, 0, stream>>>(ws + OFF_LP, ws + OFF_L2);
  k_split<<<1024, 256, 0, stream>>>(ws + OFF_LP, ws + OFF_L2, Aimg);
  k_smallmats<<<1, 64, 0, stream>>>(W_in, b_in, theta, ws);
  k_temporal<<<TSTEPS, 64, 0, stream>>>(emb_day, emb_week, midx, widx,
                                        ws + OFF_TEMP, ws + OFF_PE);
  // --- main pipeline ---
  k_gemm_mfma<<<1152, 256, 0, stream>>>(X, Aimg, ws, out_sp);
  k_final<<<ROWS / 4, 256, 0, stream>>>(X, W_in, b_in, cheb_bias, ln_g, ln_b,
                                        ws + OFF_TEMP, ws + OFF_PE,
                                        ws + OFF_W02, ws + OFF_B02,
                                        out_te, out_sp);
}